// Round 1
// 179.202 us; speedup vs baseline: 1.0292x; 1.0292x over previous
//
#include <hip/hip_runtime.h>
#include <hip/hip_bf16.h>

#define NN 4096
#define FIN 128
#define FOUT 64
#define NH 8
#define KS 4          // K splits (1024 keys per block)
#define QT 32         // Q rows per block

typedef float f32x4 __attribute__((ext_vector_type(4)));
typedef _Float16 f16x8 __attribute__((ext_vector_type(8)));
typedef _Float16 h2 __attribute__((ext_vector_type(2)));
typedef unsigned long long u64;

static __device__ __forceinline__ h2 as_h2(unsigned u) { return __builtin_bit_cast(h2, u); }
static __device__ __forceinline__ unsigned as_u32(h2 v) { return __builtin_bit_cast(unsigned, v); }

// ---------------- K0: fused mask + Wc (both roles LDS-free -> no occupancy coupling).
// Blocks 0..2047: topology -> bitmask streaming. Blocks 2048..2087: Wc[128][80].
__global__ __launch_bounds__(256) void maskwc_kernel(
    const float* __restrict__ topo, u64* __restrict__ mb,
    const float* __restrict__ proj, const float* __restrict__ score_src,
    const float* __restrict__ score_dst, const float* __restrict__ skip_w,
    float* __restrict__ Wc) {
    const int tid = threadIdx.x;
    if (blockIdx.x < 2048) {               // ---- mask role
        const int w = blockIdx.x * 4 + (tid >> 6);
        const int lane = tid & 63;
        size_t base = (size_t)w * 32;
#pragma unroll 4
        for (int it = 0; it < 32; ++it) {
            size_t u = base + it;
            float t = topo[u * 64 + lane];
            u64 b = __ballot(t > -0.5e9f);
            if (lane == 0) mb[u] = b;
        }
        return;
    }
    // ---- wc role
    int idx = (blockIdx.x - 2048) * 256 + tid;
    if (idx >= FIN * 80) return;
    int i = idx / 80, c = idx % 80;
    float v = 0.f;
    if (c < 16) {
        int h = c & 7;
        const float* w = (c < 8 ? score_src : score_dst) + h * FOUT;
        const float* p = proj + (size_t)h * FIN * FOUT + (size_t)i * FOUT;
        for (int f = 0; f < FOUT; ++f) v += p[f] * w[f];
    } else {
        int f = c - 16;
        for (int h = 0; h < NH; ++h) v += skip_w[(size_t)(h * FOUT + f) * FIN + i];
        v *= 0.125f;
    }
    Wc[i * 80 + c] = v;
}

// ---------------- K1: x@Wc -> skipm (in d_out), E/F fp16 planes, Cc packed fp16, xb fp16
// C1,C2 pre-scaled by 1/8 (per-row constant, cancels exactly in the softmax ratio) so
// all fp16 products C1*E, C2*F stay far below 65504 (bound ~600 at 1.5x sigma margin).
__global__ __launch_bounds__(256) void scores_kernel(
    const float* __restrict__ x, const float* __restrict__ Wc,
    float* __restrict__ skipm, _Float16* __restrict__ Eh, _Float16* __restrict__ Fh,
    unsigned* __restrict__ Cc, _Float16* __restrict__ xb) {
    __shared__ float wcs[FIN][80];
    __shared__ float xs[16][FIN + 5];
    const int n0 = blockIdx.x * 16;
    const int tid = threadIdx.x;
    for (int i = tid; i < FIN * 80 / 4; i += 256)
        ((float4*)&wcs[0][0])[i] = ((const float4*)Wc)[i];
    const float4* xsrc = (const float4*)(x + (size_t)n0 * FIN);
    for (int i = tid; i < 16 * FIN / 4; i += 256) {
        int r = i >> 5, c4 = i & 31;
        *(float4*)&xs[r][c4 * 4] = xsrc[i];
    }
    __syncthreads();
    const int r = tid & 15;
    const int g = tid >> 4;
    float acc[4];
    float sa = 0.f;
#pragma unroll
    for (int j = 0; j < 4; ++j) acc[j] = 0.f;
#pragma unroll 4
    for (int i = 0; i < FIN; ++i) {
        float xv = xs[r][i];
        float4 p = *(float4*)&wcs[i][16 + g * 4];
        float qv = wcs[i][g];
        acc[0] += xv * p.x; acc[1] += xv * p.y; acc[2] += xv * p.z; acc[3] += xv * p.w;
        sa += xv * qv;
    }
    int n = n0 + r;
#pragma unroll
    for (int j = 0; j < 4; ++j) skipm[(size_t)n * FOUT + g * 4 + j] = acc[j];
    if (g < 8) {
        _Float16 c1 = (_Float16)(expf(sa) * 0.125f);
        _Float16 c2 = (_Float16)(expf(0.2f * sa) * 0.125f);
        unsigned short u1 = __builtin_bit_cast(unsigned short, c1);
        unsigned short u2 = __builtin_bit_cast(unsigned short, c2);
        Cc[(size_t)g * NN + n] = ((unsigned)u2 << 16) | (unsigned)u1;
    } else {
        int h = g - 8;
        Eh[(size_t)h * NN + n] = (_Float16)expf(sa);
        Fh[(size_t)h * NN + n] = (_Float16)expf(0.2f * sa);
    }
    {
        int row = tid >> 4, col0 = (tid & 15) * 8;
        const float* src = &xs[row][col0];
        f16x8 b0;
#pragma unroll
        for (int j = 0; j < 8; ++j) b0[j] = (_Float16)src[j];
        *(f16x8*)(xb + (size_t)(n0 + row) * FIN + col0) = b0;
    }
}

// ---------------- K2: Vt[h][f][n] = proj[h]^T @ x^T via fp16 MFMA
__global__ __launch_bounds__(256) void vt_kernel(
    const float* __restrict__ proj, const _Float16* __restrict__ xb,
    _Float16* __restrict__ Vt) {
    __shared__ _Float16 pT[FOUT][FIN + 8];
    const int tid = threadIdx.x;
    const int h = blockIdx.x >> 6;
    const int ng = blockIdx.x & 63;
    for (int idx = tid; idx < FIN * FOUT; idx += 256) {
        int i = idx >> 6, f = idx & 63;
        pT[f][i] = (_Float16)proj[(size_t)h * FIN * FOUT + idx];
    }
    __syncthreads();
    const int wave = tid >> 6, lane = tid & 63, q = lane >> 4, li = lane & 15;
    const int nb = ng * 64 + wave * 16;
    f32x4 acc[4];
#pragma unroll
    for (int n = 0; n < 4; ++n) acc[n] = (f32x4){0.f, 0.f, 0.f, 0.f};
#pragma unroll
    for (int kt = 0; kt < 4; ++kt) {
        f16x8 bfrag = *(const f16x8*)(xb + (size_t)(nb + li) * FIN + kt * 32 + q * 8);
#pragma unroll
        for (int ft = 0; ft < 4; ++ft) {
            f16x8 afrag = *(const f16x8*)&pT[ft * 16 + li][kt * 32 + q * 8];
            acc[ft] = __builtin_amdgcn_mfma_f32_16x16x32_f16(afrag, bfrag, acc[ft], 0, 0, 0);
        }
    }
#pragma unroll
    for (int ft = 0; ft < 4; ++ft)
#pragma unroll
        for (int reg = 0; reg < 4; ++reg)
            Vt[((size_t)h * FOUT + ft * 16 + q * 4 + reg) * NN + nb + li] = (_Float16)acc[ft][reg];
}

// ---------------- K3: attention: head-per-wave, wave-private LDS-DMA double buffer.
// P computed 2-elems-per-instruction in packed fp16: pk_mul x2 + pk_max + and-mask.
// Mask halfwords expanded from bitmask via mul-spread + v_perm (no f32 scalar path).
// VMEM count per chunk identical to prior version -> vmcnt(4) pipeline untouched.
__attribute__((amdgpu_waves_per_eu(4)))
__global__ __launch_bounds__(256) void attn_kernel(
    const u64* __restrict__ maskbits, const _Float16* __restrict__ Vtg,
    const _Float16* __restrict__ Ehg, const _Float16* __restrict__ Fhg,
    const unsigned* __restrict__ Ccg,
    __hip_bfloat16* __restrict__ accP, float* __restrict__ rsP) {
    __shared__ u64 maskS[QT][17];         // 4.4 KB
    __shared__ char vA[4][4096];          // 16 KB: per-wave buffer A
    __shared__ char vB[4][4096];          // 16 KB: per-wave buffer B
    const int tid = threadIdx.x;
    const int w = tid >> 6;
    const int lane = tid & 63, q = lane >> 4, li = lane & 15;
    const int qt = blockIdx.x >> 3, ks = (blockIdx.x >> 1) & 3, hb = blockIdx.x & 1;
    const int h = hb * 4 + w;
    const int row0 = qt * QT;
    const int kb0 = ks * 1024;

    const int r_ = lane >> 2;
    const int sg = ((lane & 3) - (r_ >> 1)) & 3;
    const size_t laneoff = (size_t)r_ * NN + sg * 8;            // fp16 units
    const int rdoff = li * 64 + ((q + (li >> 1)) & 3) * 16;     // bytes

    const _Float16* vb = Vtg + (size_t)h * (FOUT * NN) + kb0;
    const _Float16* Ehq = Ehg + (size_t)h * NN + kb0 + q * 8;
    const _Float16* Fhq = Fhg + (size_t)h * NN + kb0 + q * 8;

#define DMA_TILE(DST, KT) do {                                                     \
    _Pragma("unroll")                                                              \
    for (int c = 0; c < 4; ++c) {                                                  \
        const _Float16* g_ = vb + (size_t)c * (16 * NN) + (KT) * 32 + laneoff;     \
        __builtin_amdgcn_global_load_lds(                                          \
            (const __attribute__((address_space(1))) void*)g_,                     \
            (__attribute__((address_space(3))) void*)&DST[w][c * 1024], 16, 0, 0); \
    }                                                                              \
} while (0)

    DMA_TILE(vA, 0);
    {   // stage 32 rows x 16 mask words (512 words, 2 per thread)
        int i0 = tid, i1 = tid + 256;
        maskS[i0 >> 4][i0 & 15] = maskbits[(size_t)(row0 + (i0 >> 4)) * 64 + ks * 16 + (i0 & 15)];
        maskS[i1 >> 4][i1 & 15] = maskbits[(size_t)(row0 + (i1 >> 4)) * 64 + ks * 16 + (i1 & 15)];
    }
    __syncthreads();                      // also drains DMA(0)

    h2 c1h[2], c2h[2];
#pragma unroll
    for (int rt = 0; rt < 2; ++rt) {
        unsigned cw = Ccg[(size_t)h * NN + row0 + rt * 16 + li];
        c1h[rt] = as_h2((cw << 16) | (cw & 0xffffu));
        c2h[rt] = as_h2((cw >> 16) | (cw & 0xffff0000u));
    }
    f16x8 ones;
#pragma unroll
    for (int j = 0; j < 8; ++j) ones[j] = (_Float16)1.0f;

    f32x4 acc[2][4];
    f32x4 rsacc[2];
#pragma unroll
    for (int rt = 0; rt < 2; ++rt) {
#pragma unroll
        for (int n = 0; n < 4; ++n) acc[rt][n] = (f32x4){0.f, 0.f, 0.f, 0.f};
        rsacc[rt] = (f32x4){0.f, 0.f, 0.f, 0.f};
    }

#define CHUNK_BODY(SRC, DSTN, KT) do {                                                        \
    uint4 ea_ = *(const uint4*)(Ehq + (KT) * 32);                                             \
    uint4 fa_ = *(const uint4*)(Fhq + (KT) * 32);                                             \
    asm volatile("" ::: "memory");             /* pin E/F loads before the DMA */             \
    DMA_TILE(DSTN, ((KT) + 1) & 31);                                                          \
    asm volatile("s_waitcnt vmcnt(4)" ::: "memory");                                          \
    f16x8 vf_[4];                                                                             \
    _Pragma("unroll")                                                                         \
    for (int n = 0; n < 4; ++n)                                                               \
        vf_[n] = *(const f16x8*)&SRC[w][n * 1024 + rdoff];                                    \
    unsigned ew_[4] = {ea_.x, ea_.y, ea_.z, ea_.w};                                           \
    unsigned fw_[4] = {fa_.x, fa_.y, fa_.z, fa_.w};                                           \
    _Pragma("unroll")                                                                         \
    for (int rt = 0; rt < 2; ++rt) {                                                          \
        u64 mw_ = maskS[rt * 16 + li][(KT) >> 1];                                             \
        unsigned mm_ = (unsigned)(mw_ >> (((KT) & 1) * 32 + q * 8)) & 0xffu;                  \
        unsigned blo_ = ((mm_ & 0xFu) * 0x204081u) & 0x01010101u;                             \
        unsigned bhi_ = ((mm_ >> 4) * 0x204081u) & 0x01010101u;                               \
        blo_ *= 0xFFu; bhi_ *= 0xFFu;                                                         \
        unsigned mk_[4] = {__builtin_amdgcn_perm(0u, blo_, 0x01010000u),                      \
                           __builtin_amdgcn_perm(0u, blo_, 0x03030202u),                      \
                           __builtin_amdgcn_perm(0u, bhi_, 0x01010000u),                      \
                           __builtin_amdgcn_perm(0u, bhi_, 0x03030202u)};                     \
        union { f16x8 v; unsigned u[4]; } pf_;                                                \
        _Pragma("unroll")                                                                     \
        for (int j2 = 0; j2 < 4; ++j2) {                                                      \
            h2 t_ = c1h[rt] * as_h2(ew_[j2]);                                                 \
            h2 u_ = c2h[rt] * as_h2(fw_[j2]);                                                 \
            h2 p_ = __builtin_elementwise_max(t_, u_);                                        \
            pf_.u[j2] = as_u32(p_) & mk_[j2];                                                 \
        }                                                                                     \
        rsacc[rt] = __builtin_amdgcn_mfma_f32_16x16x32_f16(pf_.v, ones, rsacc[rt], 0, 0, 0);  \
        _Pragma("unroll")                                                                     \
        for (int n = 0; n < 4; ++n)                                                           \
            acc[rt][n] = __builtin_amdgcn_mfma_f32_16x16x32_f16(pf_.v, vf_[n], acc[rt][n],    \
                                                                0, 0, 0);                     \
    }                                                                                         \
} while (0)

#pragma unroll 1
    for (int kt = 0; kt < 32; kt += 2) {
        CHUNK_BODY(vA, vB, kt);
        CHUNK_BODY(vB, vA, kt + 1);
    }
#undef CHUNK_BODY
#undef DMA_TILE

#pragma unroll
    for (int rt = 0; rt < 2; ++rt) {
        if (li == 0) {
#pragma unroll
            for (int reg = 0; reg < 4; ++reg)
                rsP[(size_t)(ks * NH + h) * NN + row0 + rt * 16 + q * 4 + reg] = rsacc[rt][reg];
        }
        __hip_bfloat16* ap = accP + ((size_t)(ks * NH + h) * NN + row0 + rt * 16) * 64;
#pragma unroll
        for (int n = 0; n < 4; ++n)
#pragma unroll
            for (int reg = 0; reg < 4; ++reg)
                ap[(q * 4 + reg) * 64 + n * 16 + li] = __float2bfloat16(acc[rt][n][reg]);
    }
}

// ---------------- K4: combine k-split partials + mean heads + skip + LeakyReLU
__global__ __launch_bounds__(256) void combine_kernel(
    const __hip_bfloat16* __restrict__ accP, const float* __restrict__ rsP,
    float* __restrict__ out) {
    int idx = blockIdx.x * 256 + threadIdx.x;      // 262144
    int row = idx >> 6, f = idx & 63;
    float s = 0.f;
#pragma unroll 1
    for (int h = 0; h < NH; ++h) {
        float a = 0.f, r = 0.f;
#pragma unroll
        for (int k = 0; k < KS; ++k) {
            a += __bfloat162float(accP[((size_t)(k * NH + h) * NN + row) * 64 + f]);
            r += rsP[(size_t)(k * NH + h) * NN + row];
        }
        s += a / r;
    }
    float v = s * 0.125f + out[idx];               // out currently holds skipm
    out[idx] = fmaxf(v, 0.2f * v);
}

extern "C" void kernel_launch(void* const* d_in, const int* in_sizes, int n_in,
                              void* d_out, int out_size, void* d_ws, size_t ws_size,
                              hipStream_t stream) {
    (void)in_sizes; (void)n_in; (void)out_size; (void)ws_size;
    const float* x         = (const float*)d_in[0];   // [4096,128]
    const float* topology  = (const float*)d_in[1];   // [4096,4096]
    const float* proj      = (const float*)d_in[2];   // [8,128,64]
    const float* score_src = (const float*)d_in[3];   // [8,64]
    const float* score_dst = (const float*)d_in[4];   // [8,64]
    const float* skip_w    = (const float*)d_in[5];   // [512,128]
    float* out = (float*)d_out;                       // [4096,64]

    char* ws = (char*)d_ws;
    _Float16* xb   = (_Float16*)ws;                            // 1 MB
    _Float16* Vt   = (_Float16*)(ws + 1048576);                // 4 MB
    _Float16* Eh   = (_Float16*)(ws + 5242880);                // 64 KB
    _Float16* Fh   = (_Float16*)(ws + 5308416);                // 64 KB
    unsigned* Cc   = (unsigned*)(ws + 5373952);                // 128 KB
    float* Wc      = (float*)(ws + 5505024);                   // 40 KB
    u64* maskbits  = (u64*)(ws + 5545984);                     // 2 MB
    float* rsP     = (float*)(ws + 7643136);                   // 512 KB
    __hip_bfloat16* accP = (__hip_bfloat16*)(ws + 8167424);    // 16 MB (end ~24.9 MB)
    float* skipm = out;   // skip GEMM lives in d_out; combine consumes & overwrites

    maskwc_kernel<<<2088, 256, 0, stream>>>(topology, maskbits, proj, score_src,
                                            score_dst, skip_w, Wc);
    scores_kernel<<<256, 256, 0, stream>>>(x, Wc, skipm, Eh, Fh, Cc, xb);
    vt_kernel<<<512, 256, 0, stream>>>(proj, xb, Vt);
    attn_kernel<<<1024, 256, 0, stream>>>(maskbits, Vt, Eh, Fh, Cc, accP, rsP);
    combine_kernel<<<1024, 256, 0, stream>>>(accP, rsP, out);
}

// Round 2
// 175.777 us; speedup vs baseline: 1.0493x; 1.0195x over previous
//
#include <hip/hip_runtime.h>
#include <hip/hip_bf16.h>

#define NN 4096
#define FIN 128
#define FOUT 64
#define NH 8
#define KS 4          // K splits (1024 keys per block)
#define QT 32         // Q rows per block

typedef float f32x4 __attribute__((ext_vector_type(4)));
typedef _Float16 f16x8 __attribute__((ext_vector_type(8)));
typedef _Float16 h2 __attribute__((ext_vector_type(2)));
typedef unsigned long long u64;

static __device__ __forceinline__ h2 as_h2(unsigned u) { return __builtin_bit_cast(h2, u); }
static __device__ __forceinline__ unsigned as_u32(h2 v) { return __builtin_bit_cast(unsigned, v); }

// ---------------- K0: fused mask + Wc (both roles LDS-free -> no occupancy coupling).
// Blocks 0..2047: topology -> bitmask streaming. Blocks 2048..2087: Wc[128][80].
__global__ __launch_bounds__(256) void maskwc_kernel(
    const float* __restrict__ topo, u64* __restrict__ mb,
    const float* __restrict__ proj, const float* __restrict__ score_src,
    const float* __restrict__ score_dst, const float* __restrict__ skip_w,
    float* __restrict__ Wc) {
    const int tid = threadIdx.x;
    if (blockIdx.x < 2048) {               // ---- mask role
        const int w = blockIdx.x * 4 + (tid >> 6);
        const int lane = tid & 63;
        size_t base = (size_t)w * 32;
#pragma unroll 4
        for (int it = 0; it < 32; ++it) {
            size_t u = base + it;
            float t = topo[u * 64 + lane];
            u64 b = __ballot(t > -0.5e9f);
            if (lane == 0) mb[u] = b;
        }
        return;
    }
    // ---- wc role
    int idx = (blockIdx.x - 2048) * 256 + tid;
    if (idx >= FIN * 80) return;
    int i = idx / 80, c = idx % 80;
    float v = 0.f;
    if (c < 16) {
        int h = c & 7;
        const float* w = (c < 8 ? score_src : score_dst) + h * FOUT;
        const float* p = proj + (size_t)h * FIN * FOUT + (size_t)i * FOUT;
        for (int f = 0; f < FOUT; ++f) v += p[f] * w[f];
    } else {
        int f = c - 16;
        for (int h = 0; h < NH; ++h) v += skip_w[(size_t)(h * FOUT + f) * FIN + i];
        v *= 0.125f;
    }
    Wc[i * 80 + c] = v;
}

// ---------------- K1: x@Wc -> skipm (in d_out), E/F fp16 planes, Cc packed fp16, xb fp16
// C1,C2 pre-scaled by 1/8 (per-row constant, cancels exactly in the softmax ratio) so
// all fp16 products C1*E, C2*F stay far below 65504 (bound ~600 at 1.5x sigma margin).
__global__ __launch_bounds__(256) void scores_kernel(
    const float* __restrict__ x, const float* __restrict__ Wc,
    float* __restrict__ skipm, _Float16* __restrict__ Eh, _Float16* __restrict__ Fh,
    unsigned* __restrict__ Cc, _Float16* __restrict__ xb) {
    __shared__ float wcs[FIN][80];
    __shared__ float xs[16][FIN + 5];
    const int n0 = blockIdx.x * 16;
    const int tid = threadIdx.x;
    for (int i = tid; i < FIN * 80 / 4; i += 256)
        ((float4*)&wcs[0][0])[i] = ((const float4*)Wc)[i];
    const float4* xsrc = (const float4*)(x + (size_t)n0 * FIN);
    for (int i = tid; i < 16 * FIN / 4; i += 256) {
        int r = i >> 5, c4 = i & 31;
        *(float4*)&xs[r][c4 * 4] = xsrc[i];
    }
    __syncthreads();
    const int r = tid & 15;
    const int g = tid >> 4;
    float acc[4];
    float sa = 0.f;
#pragma unroll
    for (int j = 0; j < 4; ++j) acc[j] = 0.f;
#pragma unroll 4
    for (int i = 0; i < FIN; ++i) {
        float xv = xs[r][i];
        float4 p = *(float4*)&wcs[i][16 + g * 4];
        float qv = wcs[i][g];
        acc[0] += xv * p.x; acc[1] += xv * p.y; acc[2] += xv * p.z; acc[3] += xv * p.w;
        sa += xv * qv;
    }
    int n = n0 + r;
#pragma unroll
    for (int j = 0; j < 4; ++j) skipm[(size_t)n * FOUT + g * 4 + j] = acc[j];
    if (g < 8) {
        _Float16 c1 = (_Float16)(expf(sa) * 0.125f);
        _Float16 c2 = (_Float16)(expf(0.2f * sa) * 0.125f);
        unsigned short u1 = __builtin_bit_cast(unsigned short, c1);
        unsigned short u2 = __builtin_bit_cast(unsigned short, c2);
        Cc[(size_t)g * NN + n] = ((unsigned)u2 << 16) | (unsigned)u1;
    } else {
        int h = g - 8;
        Eh[(size_t)h * NN + n] = (_Float16)expf(sa);
        Fh[(size_t)h * NN + n] = (_Float16)expf(0.2f * sa);
    }
    {
        int row = tid >> 4, col0 = (tid & 15) * 8;
        const float* src = &xs[row][col0];
        f16x8 b0;
#pragma unroll
        for (int j = 0; j < 8; ++j) b0[j] = (_Float16)src[j];
        *(f16x8*)(xb + (size_t)(n0 + row) * FIN + col0) = b0;
    }
}

// ---------------- K2: Vt[h][f][n] = proj[h]^T @ x^T via fp16 MFMA
__global__ __launch_bounds__(256) void vt_kernel(
    const float* __restrict__ proj, const _Float16* __restrict__ xb,
    _Float16* __restrict__ Vt) {
    __shared__ _Float16 pT[FOUT][FIN + 8];
    const int tid = threadIdx.x;
    const int h = blockIdx.x >> 6;
    const int ng = blockIdx.x & 63;
    for (int idx = tid; idx < FIN * FOUT; idx += 256) {
        int i = idx >> 6, f = idx & 63;
        pT[f][i] = (_Float16)proj[(size_t)h * FIN * FOUT + idx];
    }
    __syncthreads();
    const int wave = tid >> 6, lane = tid & 63, q = lane >> 4, li = lane & 15;
    const int nb = ng * 64 + wave * 16;
    f32x4 acc[4];
#pragma unroll
    for (int n = 0; n < 4; ++n) acc[n] = (f32x4){0.f, 0.f, 0.f, 0.f};
#pragma unroll
    for (int kt = 0; kt < 4; ++kt) {
        f16x8 bfrag = *(const f16x8*)(xb + (size_t)(nb + li) * FIN + kt * 32 + q * 8);
#pragma unroll
        for (int ft = 0; ft < 4; ++ft) {
            f16x8 afrag = *(const f16x8*)&pT[ft * 16 + li][kt * 32 + q * 8];
            acc[ft] = __builtin_amdgcn_mfma_f32_16x16x32_f16(afrag, bfrag, acc[ft], 0, 0, 0);
        }
    }
#pragma unroll
    for (int ft = 0; ft < 4; ++ft)
#pragma unroll
        for (int reg = 0; reg < 4; ++reg)
            Vt[((size_t)h * FOUT + ft * 16 + q * 4 + reg) * NN + nb + li] = (_Float16)acc[ft][reg];
}

// ---------------- K3: attention: head-per-wave, wave-private LDS-DMA double buffer.
// P computed 2-elems-per-instruction in packed fp16. E/F loads are software-pipelined
// one chunk ahead (two register sets through the unroll-2 body) so the per-chunk
// s_waitcnt vmcnt(6) only ever drains ops issued a full chunk earlier — no fresh L2
// latency on the critical path. Mask word hoisted (shared by the chunk pair).
__attribute__((amdgpu_waves_per_eu(4)))
__global__ __launch_bounds__(256) void attn_kernel(
    const u64* __restrict__ maskbits, const _Float16* __restrict__ Vtg,
    const _Float16* __restrict__ Ehg, const _Float16* __restrict__ Fhg,
    const unsigned* __restrict__ Ccg,
    __hip_bfloat16* __restrict__ accP, float* __restrict__ rsP) {
    __shared__ u64 maskS[QT][17];         // 4.4 KB
    __shared__ char vA[4][4096];          // 16 KB: per-wave buffer A
    __shared__ char vB[4][4096];          // 16 KB: per-wave buffer B
    const int tid = threadIdx.x;
    const int w = tid >> 6;
    const int lane = tid & 63, q = lane >> 4, li = lane & 15;
    const int qt = blockIdx.x >> 3, ks = (blockIdx.x >> 1) & 3, hb = blockIdx.x & 1;
    const int h = hb * 4 + w;
    const int row0 = qt * QT;
    const int kb0 = ks * 1024;

    const int r_ = lane >> 2;
    const int sg = ((lane & 3) - (r_ >> 1)) & 3;
    const size_t laneoff = (size_t)r_ * NN + sg * 8;            // fp16 units
    const int rdoff = li * 64 + ((q + (li >> 1)) & 3) * 16;     // bytes

    const _Float16* vb = Vtg + (size_t)h * (FOUT * NN) + kb0;
    const _Float16* Ehq = Ehg + (size_t)h * NN + kb0 + q * 8;
    const _Float16* Fhq = Fhg + (size_t)h * NN + kb0 + q * 8;

#define DMA_TILE(DST, KT) do {                                                     \
    _Pragma("unroll")                                                              \
    for (int c = 0; c < 4; ++c) {                                                  \
        const _Float16* g_ = vb + (size_t)c * (16 * NN) + (KT) * 32 + laneoff;     \
        __builtin_amdgcn_global_load_lds(                                          \
            (const __attribute__((address_space(1))) void*)g_,                     \
            (__attribute__((address_space(3))) void*)&DST[w][c * 1024], 16, 0, 0); \
    }                                                                              \
} while (0)

    // Prologue: EF(0) into register set A, DMA(0) into vA; __syncthreads drains both.
    uint4 eaA = *(const uint4*)(Ehq);
    uint4 faA = *(const uint4*)(Fhq);
    uint4 eaB, faB;
    DMA_TILE(vA, 0);
    {   // stage 32 rows x 16 mask words (512 words, 2 per thread)
        int i0 = tid, i1 = tid + 256;
        maskS[i0 >> 4][i0 & 15] = maskbits[(size_t)(row0 + (i0 >> 4)) * 64 + ks * 16 + (i0 & 15)];
        maskS[i1 >> 4][i1 & 15] = maskbits[(size_t)(row0 + (i1 >> 4)) * 64 + ks * 16 + (i1 & 15)];
    }
    __syncthreads();                      // drains DMA(0) + EF(0)

    h2 c1h[2], c2h[2];
#pragma unroll
    for (int rt = 0; rt < 2; ++rt) {
        unsigned cw = Ccg[(size_t)h * NN + row0 + rt * 16 + li];
        c1h[rt] = as_h2((cw << 16) | (cw & 0xffffu));
        c2h[rt] = as_h2((cw >> 16) | (cw & 0xffff0000u));
    }
    f16x8 ones;
#pragma unroll
    for (int j = 0; j < 8; ++j) ones[j] = (_Float16)1.0f;

    f32x4 acc[2][4];
    f32x4 rsacc[2];
#pragma unroll
    for (int rt = 0; rt < 2; ++rt) {
#pragma unroll
        for (int n = 0; n < 4; ++n) acc[rt][n] = (f32x4){0.f, 0.f, 0.f, 0.f};
        rsacc[rt] = (f32x4){0.f, 0.f, 0.f, 0.f};
    }

// EAU/FAU: E/F values for THIS chunk (already resident / completing via the wait).
// EAN/FAN: registers receiving the NEXT chunk's E/F (issued before this chunk's DMA).
#define CHUNK_BODY(SRC, DSTN, KT, EAU, FAU, EAN, FAN) do {                                    \
    EAN = *(const uint4*)(Ehq + (((KT) + 1) & 31) * 32);                                      \
    FAN = *(const uint4*)(Fhq + (((KT) + 1) & 31) * 32);                                      \
    asm volatile("" ::: "memory");             /* pin EF prefetch before the DMA */           \
    DMA_TILE(DSTN, ((KT) + 1) & 31);                                                          \
    asm volatile("s_waitcnt vmcnt(6)" ::: "memory");                                          \
    f16x8 vf_[4];                                                                             \
    _Pragma("unroll")                                                                         \
    for (int n = 0; n < 4; ++n)                                                               \
        vf_[n] = *(const f16x8*)&SRC[w][n * 1024 + rdoff];                                    \
    unsigned ew_[4] = {EAU.x, EAU.y, EAU.z, EAU.w};                                           \
    unsigned fw_[4] = {FAU.x, FAU.y, FAU.z, FAU.w};                                           \
    _Pragma("unroll")                                                                         \
    for (int rt = 0; rt < 2; ++rt) {                                                          \
        u64 mw_ = (rt == 0) ? mw0_ : mw1_;                                                    \
        unsigned mm_ = (unsigned)(mw_ >> (((KT) & 1) * 32 + q * 8)) & 0xffu;                  \
        unsigned blo_ = ((mm_ & 0xFu) * 0x204081u) & 0x01010101u;                             \
        unsigned bhi_ = ((mm_ >> 4) * 0x204081u) & 0x01010101u;                               \
        blo_ *= 0xFFu; bhi_ *= 0xFFu;                                                         \
        unsigned mk_[4] = {__builtin_amdgcn_perm(0u, blo_, 0x01010000u),                      \
                           __builtin_amdgcn_perm(0u, blo_, 0x03030202u),                      \
                           __builtin_amdgcn_perm(0u, bhi_, 0x01010000u),                      \
                           __builtin_amdgcn_perm(0u, bhi_, 0x03030202u)};                     \
        union { f16x8 v; unsigned u[4]; } pf_;                                                \
        _Pragma("unroll")                                                                     \
        for (int j2 = 0; j2 < 4; ++j2) {                                                      \
            h2 t_ = c1h[rt] * as_h2(ew_[j2]);                                                 \
            h2 u_ = c2h[rt] * as_h2(fw_[j2]);                                                 \
            h2 p_ = __builtin_elementwise_max(t_, u_);                                        \
            pf_.u[j2] = as_u32(p_) & mk_[j2];                                                 \
        }                                                                                     \
        rsacc[rt] = __builtin_amdgcn_mfma_f32_16x16x32_f16(pf_.v, ones, rsacc[rt], 0, 0, 0);  \
        _Pragma("unroll")                                                                     \
        for (int n = 0; n < 4; ++n)                                                           \
            acc[rt][n] = __builtin_amdgcn_mfma_f32_16x16x32_f16(pf_.v, vf_[n], acc[rt][n],    \
                                                                0, 0, 0);                     \
    }                                                                                         \
} while (0)

#pragma unroll 1
    for (int kt = 0; kt < 32; kt += 2) {
        u64 mw0_ = maskS[li][kt >> 1];              // shared by the chunk pair (rt=0)
        u64 mw1_ = maskS[16 + li][kt >> 1];         // (rt=1)
        CHUNK_BODY(vA, vB, kt, eaA, faA, eaB, faB);
        CHUNK_BODY(vB, vA, kt + 1, eaB, faB, eaA, faA);
    }
#undef CHUNK_BODY
#undef DMA_TILE

#pragma unroll
    for (int rt = 0; rt < 2; ++rt) {
        if (li == 0) {
#pragma unroll
            for (int reg = 0; reg < 4; ++reg)
                rsP[(size_t)(ks * NH + h) * NN + row0 + rt * 16 + q * 4 + reg] = rsacc[rt][reg];
        }
        __hip_bfloat16* ap = accP + ((size_t)(ks * NH + h) * NN + row0 + rt * 16) * 64;
#pragma unroll
        for (int n = 0; n < 4; ++n)
#pragma unroll
            for (int reg = 0; reg < 4; ++reg)
                ap[(q * 4 + reg) * 64 + n * 16 + li] = __float2bfloat16(acc[rt][n][reg]);
    }
}

// ---------------- K4: combine k-split partials + mean heads + skip + LeakyReLU
__global__ __launch_bounds__(256) void combine_kernel(
    const __hip_bfloat16* __restrict__ accP, const float* __restrict__ rsP,
    float* __restrict__ out) {
    int idx = blockIdx.x * 256 + threadIdx.x;      // 262144
    int row = idx >> 6, f = idx & 63;
    float s = 0.f;
#pragma unroll 1
    for (int h = 0; h < NH; ++h) {
        float a = 0.f, r = 0.f;
#pragma unroll
        for (int k = 0; k < KS; ++k) {
            a += __bfloat162float(accP[((size_t)(k * NH + h) * NN + row) * 64 + f]);
            r += rsP[(size_t)(k * NH + h) * NN + row];
        }
        s += a / r;
    }
    float v = s * 0.125f + out[idx];               // out currently holds skipm
    out[idx] = fmaxf(v, 0.2f * v);
}

extern "C" void kernel_launch(void* const* d_in, const int* in_sizes, int n_in,
                              void* d_out, int out_size, void* d_ws, size_t ws_size,
                              hipStream_t stream) {
    (void)in_sizes; (void)n_in; (void)out_size; (void)ws_size;
    const float* x         = (const float*)d_in[0];   // [4096,128]
    const float* topology  = (const float*)d_in[1];   // [4096,4096]
    const float* proj      = (const float*)d_in[2];   // [8,128,64]
    const float* score_src = (const float*)d_in[3];   // [8,64]
    const float* score_dst = (const float*)d_in[4];   // [8,64]
    const float* skip_w    = (const float*)d_in[5];   // [512,128]
    float* out = (float*)d_out;                       // [4096,64]

    char* ws = (char*)d_ws;
    _Float16* xb   = (_Float16*)ws;                            // 1 MB
    _Float16* Vt   = (_Float16*)(ws + 1048576);                // 4 MB
    _Float16* Eh   = (_Float16*)(ws + 5242880);                // 64 KB
    _Float16* Fh   = (_Float16*)(ws + 5308416);                // 64 KB
    unsigned* Cc   = (unsigned*)(ws + 5373952);                // 128 KB
    float* Wc      = (float*)(ws + 5505024);                   // 40 KB
    u64* maskbits  = (u64*)(ws + 5545984);                     // 2 MB
    float* rsP     = (float*)(ws + 7643136);                   // 512 KB
    __hip_bfloat16* accP = (__hip_bfloat16*)(ws + 8167424);    // 16 MB (end ~24.9 MB)
    float* skipm = out;   // skip GEMM lives in d_out; combine consumes & overwrites

    maskwc_kernel<<<2088, 256, 0, stream>>>(topology, maskbits, proj, score_src,
                                            score_dst, skip_w, Wc);
    scores_kernel<<<256, 256, 0, stream>>>(x, Wc, skipm, Eh, Fh, Cc, xb);
    vt_kernel<<<512, 256, 0, stream>>>(proj, xb, Vt);
    attn_kernel<<<1024, 256, 0, stream>>>(maskbits, Vt, Eh, Fh, Cc, accP, rsP);
    combine_kernel<<<1024, 256, 0, stream>>>(accP, rsP, out);
}